// Round 4
// baseline (447.965 us; speedup 1.0000x reference)
//
#include <hip/hip_runtime.h>
#include <hip/hip_fp16.h>
#include <math.h>

#define NN 50000
#define NE 800000
#define GEPS 1e-15f
#define BN_EPS 1e-5f
#define NB 196  // covers NN+1 node entries at 256/block

struct __align__(16) EdgeRec {
    int src;
    __half w[11];   // [0..4]=conv1, [5..9]=conv2, [10]=skip
    __half pad;
};

__device__ __forceinline__ float2 h2f(int bits) {
    __half2 h = *(__half2*)&bits;
    return __half22float2(h);
}

// inv[k*3+d] = -0.5/(eps + sigma^2): [0..14]=conv1, [15..29]=conv2, [30..32]=skip
__global__ void precompute_inv(const float* __restrict__ sig1, const float* __restrict__ sig2,
                               const float* __restrict__ sigs, float* __restrict__ inv) {
    int t = threadIdx.x;
    if (t < 15)      { float s = sig1[t];      inv[t] = -0.5f / (GEPS + s * s); }
    else if (t < 30) { float s = sig2[t - 15]; inv[t] = -0.5f / (GEPS + s * s); }
    else if (t < 33) { float s = sigs[t - 30]; inv[t] = -0.5f / (GEPS + s * s); }
}

__global__ void hist_kernel(const int* __restrict__ ei, int* __restrict__ deg) {
    int e = blockIdx.x * blockDim.x + threadIdx.x;
    if (e < NE) atomicAdd(&deg[ei[NE + e]], 1);
}

// ---- two-level scan ----
__global__ void block_reduce_kernel(const int* __restrict__ deg, int* __restrict__ bsum) {
    __shared__ int sh[256];
    int t = threadIdx.x;
    int i = blockIdx.x * 256 + t;
    sh[t] = (i < NN) ? deg[i] : 0;
    __syncthreads();
    for (int off = 128; off > 0; off >>= 1) {
        if (t < off) sh[t] += sh[t + off];
        __syncthreads();
    }
    if (t == 0) bsum[blockIdx.x] = sh[0];
}

__global__ void scan_partials_kernel(int* __restrict__ bsum) {
    __shared__ int sh[256];
    int t = threadIdx.x;
    int v = (t < NB) ? bsum[t] : 0;
    sh[t] = v;
    __syncthreads();
    for (int off = 1; off < 256; off <<= 1) {
        int u = (t >= off) ? sh[t - off] : 0;
        __syncthreads();
        sh[t] += u;
        __syncthreads();
    }
    if (t < NB) bsum[t] = sh[t] - v;  // exclusive
}

// writes rowstart[0..NN] (NN+1 entries; rowstart[NN]==NE) and cursor[0..NN-1]
__global__ void block_scan_kernel(const int* __restrict__ deg, const int* __restrict__ bsum,
                                  int* __restrict__ rowstart, int* __restrict__ cursor) {
    __shared__ int sh[256];
    int t = threadIdx.x;
    int i = blockIdx.x * 256 + t;
    int v = (i < NN) ? deg[i] : 0;
    sh[t] = v;
    __syncthreads();
    for (int off = 1; off < 256; off <<= 1) {
        int u = (t >= off) ? sh[t - off] : 0;
        __syncthreads();
        sh[t] += u;
        __syncthreads();
    }
    int excl = sh[t] - v + bsum[blockIdx.x];
    if (i <= NN) rowstart[i] = excl;
    if (i < NN) cursor[i] = excl;
}

// scatter edges into CSR order as packed 32B records (src + 11 fp16 gaussian weights)
__global__ void reorder_kernel(const int* __restrict__ ei, const float* __restrict__ ea,
                               const float* __restrict__ mu1, const float* __restrict__ mu2,
                               const float* __restrict__ mus, const float* __restrict__ inv,
                               int* __restrict__ cursor, int4* __restrict__ recs) {
    int e = blockIdx.x * blockDim.x + threadIdx.x;
    if (e >= NE) return;
    int src = ei[e];
    int dst = ei[NE + e];
    float a0 = ea[e * 3 + 0], a1 = ea[e * 3 + 1], a2 = ea[e * 3 + 2];

    union { EdgeRec r; int4 q[2]; } u;
    u.r.src = src;
#pragma unroll
    for (int k = 0; k < 5; k++) {
        float d0 = a0 - mu1[k * 3 + 0], d1 = a1 - mu1[k * 3 + 1], d2 = a2 - mu1[k * 3 + 2];
        float ex = inv[k * 3] * d0 * d0 + inv[k * 3 + 1] * d1 * d1 + inv[k * 3 + 2] * d2 * d2;
        u.r.w[k] = __float2half(__expf(ex));
    }
#pragma unroll
    for (int k = 0; k < 5; k++) {
        float d0 = a0 - mu2[k * 3 + 0], d1 = a1 - mu2[k * 3 + 1], d2 = a2 - mu2[k * 3 + 2];
        float ex = inv[15 + k * 3] * d0 * d0 + inv[15 + k * 3 + 1] * d1 * d1 + inv[15 + k * 3 + 2] * d2 * d2;
        u.r.w[5 + k] = __float2half(__expf(ex));
    }
    {
        float d0 = a0 - mus[0], d1 = a1 - mus[1], d2 = a2 - mus[2];
        float ex = inv[30] * d0 * d0 + inv[31] * d1 * d1 + inv[32] * d2 * d2;
        u.r.w[10] = __float2half(__expf(ex));
    }
    u.r.pad = __float2half(0.f);

    int pos = atomicAdd(&cursor[dst], 1);
    recs[(size_t)pos * 2]     = u.q[0];
    recs[(size_t)pos * 2 + 1] = u.q[1];
}

// pass A projection: x -> PA[n][192] fp16 (0..159: g1-proj, 160..191: gs-proj),
//                    R1[n][32] fp32 (x@root1+b1), Rs[n][32] fp32 (x@roots+bs). block=256.
__global__ void projA_kernel(const float* __restrict__ x, const float* __restrict__ g1,
                             const float* __restrict__ gs, const float* __restrict__ root1,
                             const float* __restrict__ b1, const float* __restrict__ roots,
                             const float* __restrict__ bs, __half* __restrict__ PA,
                             float* __restrict__ R1, float* __restrict__ Rs) {
    const int t = threadIdx.x;
    float w[32];
    float b = 0.0f;
    if (t < 160) {
#pragma unroll
        for (int i = 0; i < 32; i++) w[i] = g1[i * 160 + t];
    } else if (t < 192) {
        int c = t - 160;
#pragma unroll
        for (int i = 0; i < 32; i++) w[i] = gs[i * 32 + c];
    } else if (t < 224) {
        int c = t - 192;
#pragma unroll
        for (int i = 0; i < 32; i++) w[i] = root1[i * 32 + c];
        b = b1[c];
    } else {
        int c = t - 224;
#pragma unroll
        for (int i = 0; i < 32; i++) w[i] = roots[i * 32 + c];
        b = bs[c];
    }
    __shared__ float xs[8 * 32];
    for (int n0 = blockIdx.x * 8; n0 < NN; n0 += gridDim.x * 8) {
        int rows = NN - n0; if (rows > 8) rows = 8;
        for (int j = t; j < rows * 32; j += 256) xs[j] = x[(size_t)n0 * 32 + j];
        __syncthreads();
        for (int r = 0; r < rows; r++) {
            float acc = b;
#pragma unroll
            for (int i = 0; i < 32; i++) acc += w[i] * xs[r * 32 + i];
            int n = n0 + r;
            if (t < 192) PA[(size_t)n * 192 + t] = __float2half(acc);
            else if (t < 224) R1[(size_t)n * 32 + (t - 192)] = acc;
            else Rs[(size_t)n * 32 + (t - 224)] = acc;
        }
        __syncthreads();
    }
}

// pass B projection: h -> PB[n][160] fp16, R2[n][32] fp32. block=192.
__global__ void projB_kernel(const float* __restrict__ h, const float* __restrict__ g2,
                             const float* __restrict__ root2, const float* __restrict__ b2,
                             __half* __restrict__ PB, float* __restrict__ R2) {
    const int t = threadIdx.x;
    float w[32];
    float b = 0.0f;
    if (t < 160) {
#pragma unroll
        for (int i = 0; i < 32; i++) w[i] = g2[i * 160 + t];
    } else {
        int c = t - 160;
#pragma unroll
        for (int i = 0; i < 32; i++) w[i] = root2[i * 32 + c];
        b = b2[c];
    }
    __shared__ float xs[8 * 32];
    for (int n0 = blockIdx.x * 8; n0 < NN; n0 += gridDim.x * 8) {
        int rows = NN - n0; if (rows > 8) rows = 8;
        for (int j = t; j < rows * 32; j += 192) xs[j] = h[(size_t)n0 * 32 + j];
        __syncthreads();
        for (int r = 0; r < rows; r++) {
            float acc = b;
#pragma unroll
            for (int i = 0; i < 32; i++) acc += w[i] * xs[r * 32 + i];
            int n = n0 + r;
            if (t < 160) PB[(size_t)n * 160 + t] = __float2half(acc);
            else R2[(size_t)n * 32 + (t - 160)] = acc;
        }
        __syncthreads();
    }
}

// CSR node-gather aggregate, software-pipelined: one wave per node, 4 groups of 16 lanes,
// each group processes edges i%4==grp TWO AT A TIME (all gather loads issued before FMAs).
// Lane owns a channel pair (half2). Fuses mean + root add + BN stats.
template <bool SKIP, int WOFF>
__global__ void agg_kernel(const int4* __restrict__ recs, const int* __restrict__ rowstart,
                           const __half2* __restrict__ P, int strideH2,
                           const float* __restrict__ R, const float* __restrict__ Rs,
                           float* __restrict__ c, float* __restrict__ cs,
                           float* __restrict__ stats) {
    const int tid = blockIdx.x * blockDim.x + threadIdx.x;
    const int lane = threadIdx.x & 63;
    const int grp = lane >> 4;        // 0..3: edge subgroup
    const int ch2 = lane & 15;        // channel pair index
    const int wavesTotal = (gridDim.x * blockDim.x) >> 6;
    const int wid = tid >> 6;

    float s1x = 0.f, s1y = 0.f, q1x = 0.f, q1y = 0.f;
    float ssx = 0.f, ssy = 0.f, qsx = 0.f, qsy = 0.f;

    for (int n = wid; n < NN; n += wavesTotal) {
        const int start = rowstart[n];
        const int end = rowstart[n + 1];
        const int d = end - start;
        float m1x = 0.f, m1y = 0.f, mSx = 0.f, mSy = 0.f;

        int i = start + grp;
        // ---- paired iterations: issue ALL loads for 2 edges, then all FMAs ----
        for (; i + 4 < end; i += 8) {
            int4 aq0 = recs[(size_t)i * 2];
            int4 aq1 = recs[(size_t)i * 2 + 1];
            int4 bq0 = recs[(size_t)(i + 4) * 2];
            int4 bq1 = recs[(size_t)(i + 4) * 2 + 1];

            const __half2* pa = P + (size_t)aq0.x * strideH2 + ch2;
            const __half2* pb = P + (size_t)bq0.x * strideH2 + ch2;
            float2 ap0 = __half22float2(pa[0]);
            float2 ap1 = __half22float2(pa[16]);
            float2 ap2 = __half22float2(pa[32]);
            float2 ap3 = __half22float2(pa[48]);
            float2 ap4 = __half22float2(pa[64]);
            float2 bp0 = __half22float2(pb[0]);
            float2 bp1 = __half22float2(pb[16]);
            float2 bp2 = __half22float2(pb[32]);
            float2 bp3 = __half22float2(pb[48]);
            float2 bp4 = __half22float2(pb[64]);
            float2 aps, bps;
            if (SKIP) { aps = __half22float2(pa[80]); bps = __half22float2(pb[80]); }

            float aw0, aw1, aw2, aw3, aw4, bw0, bw1, bw2, bw3, bw4;
            if (WOFF == 0) {
                float2 u0 = h2f(aq0.y), u1 = h2f(aq0.z), u2 = h2f(aq0.w);
                aw0 = u0.x; aw1 = u0.y; aw2 = u1.x; aw3 = u1.y; aw4 = u2.x;
                float2 v0 = h2f(bq0.y), v1 = h2f(bq0.z), v2 = h2f(bq0.w);
                bw0 = v0.x; bw1 = v0.y; bw2 = v1.x; bw3 = v1.y; bw4 = v2.x;
            } else {
                float2 u2 = h2f(aq0.w), u3 = h2f(aq1.x), u4 = h2f(aq1.y);
                aw0 = u2.y; aw1 = u3.x; aw2 = u3.y; aw3 = u4.x; aw4 = u4.y;
                float2 v2 = h2f(bq0.w), v3 = h2f(bq1.x), v4 = h2f(bq1.y);
                bw0 = v2.y; bw1 = v3.x; bw2 = v3.y; bw3 = v4.x; bw4 = v4.y;
            }
            m1x += aw0 * ap0.x + aw1 * ap1.x + aw2 * ap2.x + aw3 * ap3.x + aw4 * ap4.x;
            m1y += aw0 * ap0.y + aw1 * ap1.y + aw2 * ap2.y + aw3 * ap3.y + aw4 * ap4.y;
            m1x += bw0 * bp0.x + bw1 * bp1.x + bw2 * bp2.x + bw3 * bp3.x + bw4 * bp4.x;
            m1y += bw0 * bp0.y + bw1 * bp1.y + bw2 * bp2.y + bw3 * bp3.y + bw4 * bp4.y;
            if (SKIP) {
                float aws = h2f(aq1.z).x, bws = h2f(bq1.z).x;
                mSx += aws * aps.x + bws * bps.x;
                mSy += aws * aps.y + bws * bps.y;
            }
        }
        // ---- remainder (at most one record per group) ----
        if (i < end) {
            int4 aq0 = recs[(size_t)i * 2];
            int4 aq1 = recs[(size_t)i * 2 + 1];
            const __half2* pa = P + (size_t)aq0.x * strideH2 + ch2;
            float2 ap0 = __half22float2(pa[0]);
            float2 ap1 = __half22float2(pa[16]);
            float2 ap2 = __half22float2(pa[32]);
            float2 ap3 = __half22float2(pa[48]);
            float2 ap4 = __half22float2(pa[64]);
            float aw0, aw1, aw2, aw3, aw4;
            if (WOFF == 0) {
                float2 u0 = h2f(aq0.y), u1 = h2f(aq0.z), u2 = h2f(aq0.w);
                aw0 = u0.x; aw1 = u0.y; aw2 = u1.x; aw3 = u1.y; aw4 = u2.x;
            } else {
                float2 u2 = h2f(aq0.w), u3 = h2f(aq1.x), u4 = h2f(aq1.y);
                aw0 = u2.y; aw1 = u3.x; aw2 = u3.y; aw3 = u4.x; aw4 = u4.y;
            }
            m1x += aw0 * ap0.x + aw1 * ap1.x + aw2 * ap2.x + aw3 * ap3.x + aw4 * ap4.x;
            m1y += aw0 * ap0.y + aw1 * ap1.y + aw2 * ap2.y + aw3 * ap3.y + aw4 * ap4.y;
            if (SKIP) {
                float2 aps = __half22float2(pa[80]);
                float aws = h2f(aq1.z).x;
                mSx += aws * aps.x;
                mSy += aws * aps.y;
            }
        }

        m1x += __shfl_xor(m1x, 16, 64); m1x += __shfl_xor(m1x, 32, 64);
        m1y += __shfl_xor(m1y, 16, 64); m1y += __shfl_xor(m1y, 32, 64);
        if (SKIP) {
            mSx += __shfl_xor(mSx, 16, 64); mSx += __shfl_xor(mSx, 32, 64);
            mSy += __shfl_xor(mSy, 16, 64); mSy += __shfl_xor(mSy, 32, 64);
        }
        const float invd = 1.0f / fmaxf((float)d, 1.0f);
        if (grp == 0) {
            float2 rv = ((const float2*)(R + (size_t)n * 32))[ch2];
            float vx = m1x * invd + rv.x;
            float vy = m1y * invd + rv.y;
            ((float2*)(c + (size_t)n * 32))[ch2] = make_float2(vx, vy);
            s1x += vx; s1y += vy; q1x += vx * vx; q1y += vy * vy;
            if (SKIP) {
                float2 rs = ((const float2*)(Rs + (size_t)n * 32))[ch2];
                float wx = mSx * invd + rs.x;
                float wy = mSy * invd + rs.y;
                ((float2*)(cs + (size_t)n * 32))[ch2] = make_float2(wx, wy);
                ssx += wx; ssy += wy; qsx += wx * wx; qsy += wy * wy;
            }
        }
    }
    __shared__ float sh[128];
    const int t = threadIdx.x;
    if (t < 128) sh[t] = 0.f;
    __syncthreads();
    if (grp == 0) {
        atomicAdd(&sh[2 * ch2], s1x);       atomicAdd(&sh[2 * ch2 + 1], s1y);
        atomicAdd(&sh[32 + 2 * ch2], q1x);  atomicAdd(&sh[32 + 2 * ch2 + 1], q1y);
        if (SKIP) {
            atomicAdd(&sh[64 + 2 * ch2], ssx);  atomicAdd(&sh[64 + 2 * ch2 + 1], ssy);
            atomicAdd(&sh[96 + 2 * ch2], qsx);  atomicAdd(&sh[96 + 2 * ch2 + 1], qsy);
        }
    }
    __syncthreads();
    if (SKIP) { if (t < 128) atomicAdd(&stats[t], sh[t]); }
    else      { if (t < 64)  atomicAdd(&stats[t], sh[t]); }
}

// h = elu(bn(c1)); s = bn(cs). stats layout: [sum1|sq1|sumS|sqS]
__global__ void apply1_kernel(const float* __restrict__ c1, const float* __restrict__ cs,
                              const float* __restrict__ stats, const float* __restrict__ gam1,
                              const float* __restrict__ bet1, const float* __restrict__ gams,
                              const float* __restrict__ bets, float* __restrict__ h,
                              float* __restrict__ s_out) {
    int idx = blockIdx.x * blockDim.x + threadIdx.x;
    if (idx >= NN * 32) return;
    int ch = idx & 31;
    const float invN = 1.0f / (float)NN;
    float m1 = stats[ch] * invN;
    float v1 = stats[32 + ch] * invN - m1 * m1;
    float hv = gam1[ch] * (c1[idx] - m1) * rsqrtf(v1 + BN_EPS) + bet1[ch];
    h[idx] = hv > 0.f ? hv : (__expf(hv) - 1.f);
    float ms = stats[64 + ch] * invN;
    float vs = stats[96 + ch] * invN - ms * ms;
    s_out[idx] = gams[ch] * (cs[idx] - ms) * rsqrtf(vs + BN_EPS) + bets[ch];
}

// out = elu(bn(c2) + s)
__global__ void apply2_kernel(const float* __restrict__ c2, const float* __restrict__ s_in,
                              const float* __restrict__ stats, const float* __restrict__ gam2,
                              const float* __restrict__ bet2, float* __restrict__ out) {
    int idx = blockIdx.x * blockDim.x + threadIdx.x;
    if (idx >= NN * 32) return;
    int ch = idx & 31;
    const float invN = 1.0f / (float)NN;
    float m = stats[ch] * invN;
    float v = stats[32 + ch] * invN - m * m;
    float o = gam2[ch] * (c2[idx] - m) * rsqrtf(v + BN_EPS) + bet2[ch] + s_in[idx];
    out[idx] = o > 0.f ? o : (__expf(o) - 1.f);
}

extern "C" void kernel_launch(void* const* d_in, const int* in_sizes, int n_in,
                              void* d_out, int out_size, void* d_ws, size_t ws_size,
                              hipStream_t stream) {
    const float* x     = (const float*)d_in[0];
    const float* ea    = (const float*)d_in[1];
    const float* g1    = (const float*)d_in[2];
    const float* mu1   = (const float*)d_in[3];
    const float* sig1  = (const float*)d_in[4];
    const float* root1 = (const float*)d_in[5];
    const float* b1    = (const float*)d_in[6];
    const float* gam1  = (const float*)d_in[7];
    const float* bet1  = (const float*)d_in[8];
    const float* g2    = (const float*)d_in[9];
    const float* mu2   = (const float*)d_in[10];
    const float* sig2  = (const float*)d_in[11];
    const float* root2 = (const float*)d_in[12];
    const float* b2    = (const float*)d_in[13];
    const float* gam2  = (const float*)d_in[14];
    const float* bet2  = (const float*)d_in[15];
    const float* gs    = (const float*)d_in[16];
    const float* mus   = (const float*)d_in[17];
    const float* sigs  = (const float*)d_in[18];
    const float* roots = (const float*)d_in[19];
    const float* bs    = (const float*)d_in[20];
    const float* gams  = (const float*)d_in[21];
    const float* bets  = (const float*)d_in[22];
    const int*   ei    = (const int*)d_in[23];
    float* out = (float*)d_out;

    // ---- workspace layout ----
    char* w = (char*)d_ws;
    __half* PA   = (__half*)w;      w += (size_t)NN * 192 * 2;  // 19.2 MB (reused as PB)
    float*  R1   = (float*)w;       w += (size_t)NN * 32 * 4;   // (reused as R2)
    float*  Rs   = (float*)w;       w += (size_t)NN * 32 * 4;
    float*  c1   = (float*)w;       w += (size_t)NN * 32 * 4;   // (reused as c2)
    float*  cs   = (float*)w;       w += (size_t)NN * 32 * 4;
    float*  h    = (float*)w;       w += (size_t)NN * 32 * 4;
    float*  sbuf = (float*)w;       w += (size_t)NN * 32 * 4;
    EdgeRec* recs = (EdgeRec*)w;    w += (size_t)NE * 32;       // 25.6 MB
    int*    deg  = (int*)w;         w += (size_t)NN * 4;
    float*  stats = (float*)w;      w += 256 * 4;               // [0..127]=pass A, [128..191]=pass B
    int*    rowstart = (int*)w;     w += (size_t)(NN + 1) * 4;
    int*    cursor   = (int*)w;     w += (size_t)NN * 4;
    int*    bsum = (int*)w;         w += 256 * 4;
    float*  inv   = (float*)w;      w += 64 * 4;

    const int edgeBlocks  = (NE + 255) / 256;
    const int applyBlocks = (NN * 32 + 255) / 256;

    // deg and stats are contiguous -> one memset
    hipMemsetAsync(deg, 0, (size_t)NN * 4 + 256 * 4, stream);
    precompute_inv<<<1, 64, 0, stream>>>(sig1, sig2, sigs, inv);

    // ---- CSR build (once, shared by all 3 convs) ----
    hist_kernel<<<edgeBlocks, 256, 0, stream>>>(ei, deg);
    block_reduce_kernel<<<NB, 256, 0, stream>>>(deg, bsum);
    scan_partials_kernel<<<1, 256, 0, stream>>>(bsum);
    block_scan_kernel<<<NB, 256, 0, stream>>>(deg, bsum, rowstart, cursor);
    reorder_kernel<<<edgeBlocks, 256, 0, stream>>>(ei, ea, mu1, mu2, mus, inv, cursor,
                                                   (int4*)recs);

    // ---- pass A: conv1 + skip fused ----
    projA_kernel<<<512, 256, 0, stream>>>(x, g1, gs, root1, b1, roots, bs, PA, R1, Rs);
    agg_kernel<true, 0><<<2048, 256, 0, stream>>>((const int4*)recs, rowstart,
                                                  (const __half2*)PA, 96, R1, Rs, c1, cs, stats);
    apply1_kernel<<<applyBlocks, 256, 0, stream>>>(c1, cs, stats, gam1, bet1, gams, bets,
                                                   h, sbuf);

    // ---- pass B: conv2 on h, then out = elu(bn(c2) + s) ----
    projB_kernel<<<512, 192, 0, stream>>>(h, g2, root2, b2, PA, R1);  // PA/R1 reused
    agg_kernel<false, 5><<<2048, 256, 0, stream>>>((const int4*)recs, rowstart,
                                                   (const __half2*)PA, 80, R1, nullptr, c1,
                                                   nullptr, stats + 128);
    apply2_kernel<<<applyBlocks, 256, 0, stream>>>(c1, sbuf, stats + 128, gam2, bet2, out);
}

// Round 5
// 438.074 us; speedup vs baseline: 1.0226x; 1.0226x over previous
//
#include <hip/hip_runtime.h>
#include <hip/hip_fp16.h>
#include <math.h>

#define NN 50000
#define NE 800000
#define GEPS 1e-15f
#define BN_EPS 1e-5f
#define NB 196  // covers NN+1 node entries at 256/block

struct __align__(16) EdgeRec {
    int src;
    __half w[11];   // [0..4]=conv1, [5..9]=conv2, [10]=skip
    __half pad;
};

__device__ __forceinline__ float2 h2f(int bits) {
    __half2 h = *(__half2*)&bits;
    return __half22float2(h);
}

// inv[k*3+d] = -0.5/(eps + sigma^2): [0..14]=conv1, [15..29]=conv2, [30..32]=skip
__global__ void precompute_inv(const float* __restrict__ sig1, const float* __restrict__ sig2,
                               const float* __restrict__ sigs, float* __restrict__ inv) {
    int t = threadIdx.x;
    if (t < 15)      { float s = sig1[t];      inv[t] = -0.5f / (GEPS + s * s); }
    else if (t < 30) { float s = sig2[t - 15]; inv[t] = -0.5f / (GEPS + s * s); }
    else if (t < 33) { float s = sigs[t - 30]; inv[t] = -0.5f / (GEPS + s * s); }
}

__global__ void hist_kernel(const int* __restrict__ ei, int* __restrict__ deg) {
    int e = blockIdx.x * blockDim.x + threadIdx.x;
    if (e < NE) atomicAdd(&deg[ei[NE + e]], 1);
}

// ---- two-level scan ----
__global__ void block_reduce_kernel(const int* __restrict__ deg, int* __restrict__ bsum) {
    __shared__ int sh[256];
    int t = threadIdx.x;
    int i = blockIdx.x * 256 + t;
    sh[t] = (i < NN) ? deg[i] : 0;
    __syncthreads();
    for (int off = 128; off > 0; off >>= 1) {
        if (t < off) sh[t] += sh[t + off];
        __syncthreads();
    }
    if (t == 0) bsum[blockIdx.x] = sh[0];
}

__global__ void scan_partials_kernel(int* __restrict__ bsum) {
    __shared__ int sh[256];
    int t = threadIdx.x;
    int v = (t < NB) ? bsum[t] : 0;
    sh[t] = v;
    __syncthreads();
    for (int off = 1; off < 256; off <<= 1) {
        int u = (t >= off) ? sh[t - off] : 0;
        __syncthreads();
        sh[t] += u;
        __syncthreads();
    }
    if (t < NB) bsum[t] = sh[t] - v;  // exclusive
}

// writes rowstart[0..NN] (NN+1 entries; rowstart[NN]==NE) and cursor[0..NN-1]
__global__ void block_scan_kernel(const int* __restrict__ deg, const int* __restrict__ bsum,
                                  int* __restrict__ rowstart, int* __restrict__ cursor) {
    __shared__ int sh[256];
    int t = threadIdx.x;
    int i = blockIdx.x * 256 + t;
    int v = (i < NN) ? deg[i] : 0;
    sh[t] = v;
    __syncthreads();
    for (int off = 1; off < 256; off <<= 1) {
        int u = (t >= off) ? sh[t - off] : 0;
        __syncthreads();
        sh[t] += u;
        __syncthreads();
    }
    int excl = sh[t] - v + bsum[blockIdx.x];
    if (i <= NN) rowstart[i] = excl;
    if (i < NN) cursor[i] = excl;
}

// scatter edges into CSR order as packed 32B records (src + 11 fp16 gaussian weights)
__global__ void reorder_kernel(const int* __restrict__ ei, const float* __restrict__ ea,
                               const float* __restrict__ mu1, const float* __restrict__ mu2,
                               const float* __restrict__ mus, const float* __restrict__ inv,
                               int* __restrict__ cursor, int4* __restrict__ recs) {
    int e = blockIdx.x * blockDim.x + threadIdx.x;
    if (e >= NE) return;
    int src = ei[e];
    int dst = ei[NE + e];
    float a0 = ea[e * 3 + 0], a1 = ea[e * 3 + 1], a2 = ea[e * 3 + 2];

    union { EdgeRec r; int4 q[2]; } u;
    u.r.src = src;
#pragma unroll
    for (int k = 0; k < 5; k++) {
        float d0 = a0 - mu1[k * 3 + 0], d1 = a1 - mu1[k * 3 + 1], d2 = a2 - mu1[k * 3 + 2];
        float ex = inv[k * 3] * d0 * d0 + inv[k * 3 + 1] * d1 * d1 + inv[k * 3 + 2] * d2 * d2;
        u.r.w[k] = __float2half(__expf(ex));
    }
#pragma unroll
    for (int k = 0; k < 5; k++) {
        float d0 = a0 - mu2[k * 3 + 0], d1 = a1 - mu2[k * 3 + 1], d2 = a2 - mu2[k * 3 + 2];
        float ex = inv[15 + k * 3] * d0 * d0 + inv[15 + k * 3 + 1] * d1 * d1 + inv[15 + k * 3 + 2] * d2 * d2;
        u.r.w[5 + k] = __float2half(__expf(ex));
    }
    {
        float d0 = a0 - mus[0], d1 = a1 - mus[1], d2 = a2 - mus[2];
        float ex = inv[30] * d0 * d0 + inv[31] * d1 * d1 + inv[32] * d2 * d2;
        u.r.w[10] = __float2half(__expf(ex));
    }
    u.r.pad = __float2half(0.f);

    int pos = atomicAdd(&cursor[dst], 1);
    recs[(size_t)pos * 2]     = u.q[0];
    recs[(size_t)pos * 2 + 1] = u.q[1];
}

// pass A projection: x -> PA[n][192] fp16 (0..159: g1-proj, 160..191: gs-proj),
//                    R1[n][32] fp32 (x@root1+b1), Rs[n][32] fp32 (x@roots+bs). block=256.
__global__ void projA_kernel(const float* __restrict__ x, const float* __restrict__ g1,
                             const float* __restrict__ gs, const float* __restrict__ root1,
                             const float* __restrict__ b1, const float* __restrict__ roots,
                             const float* __restrict__ bs, __half* __restrict__ PA,
                             float* __restrict__ R1, float* __restrict__ Rs) {
    const int t = threadIdx.x;
    float w[32];
    float b = 0.0f;
    if (t < 160) {
#pragma unroll
        for (int i = 0; i < 32; i++) w[i] = g1[i * 160 + t];
    } else if (t < 192) {
        int c = t - 160;
#pragma unroll
        for (int i = 0; i < 32; i++) w[i] = gs[i * 32 + c];
    } else if (t < 224) {
        int c = t - 192;
#pragma unroll
        for (int i = 0; i < 32; i++) w[i] = root1[i * 32 + c];
        b = b1[c];
    } else {
        int c = t - 224;
#pragma unroll
        for (int i = 0; i < 32; i++) w[i] = roots[i * 32 + c];
        b = bs[c];
    }
    __shared__ float xs[8 * 32];
    for (int n0 = blockIdx.x * 8; n0 < NN; n0 += gridDim.x * 8) {
        int rows = NN - n0; if (rows > 8) rows = 8;
        for (int j = t; j < rows * 32; j += 256) xs[j] = x[(size_t)n0 * 32 + j];
        __syncthreads();
        for (int r = 0; r < rows; r++) {
            float acc = b;
#pragma unroll
            for (int i = 0; i < 32; i++) acc += w[i] * xs[r * 32 + i];
            int n = n0 + r;
            if (t < 192) PA[(size_t)n * 192 + t] = __float2half(acc);
            else if (t < 224) R1[(size_t)n * 32 + (t - 192)] = acc;
            else Rs[(size_t)n * 32 + (t - 224)] = acc;
        }
        __syncthreads();
    }
}

// pass B projection: h -> PB[n][160] fp16, R2[n][32] fp32. block=192.
__global__ void projB_kernel(const float* __restrict__ h, const float* __restrict__ g2,
                             const float* __restrict__ root2, const float* __restrict__ b2,
                             __half* __restrict__ PB, float* __restrict__ R2) {
    const int t = threadIdx.x;
    float w[32];
    float b = 0.0f;
    if (t < 160) {
#pragma unroll
        for (int i = 0; i < 32; i++) w[i] = g2[i * 160 + t];
    } else {
        int c = t - 160;
#pragma unroll
        for (int i = 0; i < 32; i++) w[i] = root2[i * 32 + c];
        b = b2[c];
    }
    __shared__ float xs[8 * 32];
    for (int n0 = blockIdx.x * 8; n0 < NN; n0 += gridDim.x * 8) {
        int rows = NN - n0; if (rows > 8) rows = 8;
        for (int j = t; j < rows * 32; j += 192) xs[j] = h[(size_t)n0 * 32 + j];
        __syncthreads();
        for (int r = 0; r < rows; r++) {
            float acc = b;
#pragma unroll
            for (int i = 0; i < 32; i++) acc += w[i] * xs[r * 32 + i];
            int n = n0 + r;
            if (t < 160) PB[(size_t)n * 160 + t] = __float2half(acc);
            else R2[(size_t)n * 32 + (t - 160)] = acc;
        }
        __syncthreads();
    }
}

// CSR node-gather aggregate. One wave per node; 8 groups of 8 lanes (group g handles
// edges i%8==g); each lane owns 4 channels (one 8B dwordx2 gather per k-chunk, 64B/group
// coalesced). Next edge record is register-prefetched so the per-iteration chain is only
// the prow gather latency. BN stats accumulate straight into LDS (low VGPR pressure).
template <bool SKIP, int WOFF>
__global__ __launch_bounds__(256, 8) void agg_kernel(
        const int4* __restrict__ recs, const int* __restrict__ rowstart,
        const char* __restrict__ P, int strideB,
        const float* __restrict__ R, const float* __restrict__ Rs,
        float* __restrict__ c, float* __restrict__ cs, float* __restrict__ stats) {
    const int tid = blockIdx.x * blockDim.x + threadIdx.x;
    const int lane = threadIdx.x & 63;
    const int grp = lane >> 3;        // 0..7: edge subgroup
    const int ch4 = lane & 7;         // 4-channel group index
    const int wavesTotal = (gridDim.x * blockDim.x) >> 6;
    const int wid = tid >> 6;

    __shared__ float sh[128];
    if (threadIdx.x < 128) sh[threadIdx.x] = 0.f;
    __syncthreads();

    for (int n = wid; n < NN; n += wavesTotal) {
        const int start = rowstart[n];
        const int end = rowstart[n + 1];
        const int d = end - start;
        float m0 = 0.f, m1 = 0.f, m2 = 0.f, m3 = 0.f;
        float mS0 = 0.f, mS1 = 0.f, mS2 = 0.f, mS3 = 0.f;

        int i = start + grp;
        if (i < end) {
            int4 q0 = recs[(size_t)i * 2];
            int4 q1 = recs[(size_t)i * 2 + 1];
            for (; i < end; i += 8) {
                // prefetch next record (in-bounds clamp: reuse current if last)
                int inext = i + 8;
                int pidx = (inext < end) ? inext : i;
                int4 nq0 = recs[(size_t)pidx * 2];
                int4 nq1 = recs[(size_t)pidx * 2 + 1];

                const int2* p = (const int2*)(P + (size_t)q0.x * strideB) + ch4;
                int2 v0 = p[0];
                int2 v1 = p[8];
                int2 v2 = p[16];
                int2 v3 = p[24];
                int2 v4 = p[32];
                int2 vsk;
                if (SKIP) vsk = p[40];

                float w0, w1, w2, w3, w4;
                if (WOFF == 0) {
                    float2 u0 = h2f(q0.y), u1 = h2f(q0.z), u2 = h2f(q0.w);
                    w0 = u0.x; w1 = u0.y; w2 = u1.x; w3 = u1.y; w4 = u2.x;
                } else {
                    float2 u2 = h2f(q0.w), u3 = h2f(q1.x), u4 = h2f(q1.y);
                    w0 = u2.y; w1 = u3.x; w2 = u3.y; w3 = u4.x; w4 = u4.y;
                }
                float2 a, b;
                a = h2f(v0.x); b = h2f(v0.y);
                m0 += w0 * a.x; m1 += w0 * a.y; m2 += w0 * b.x; m3 += w0 * b.y;
                a = h2f(v1.x); b = h2f(v1.y);
                m0 += w1 * a.x; m1 += w1 * a.y; m2 += w1 * b.x; m3 += w1 * b.y;
                a = h2f(v2.x); b = h2f(v2.y);
                m0 += w2 * a.x; m1 += w2 * a.y; m2 += w2 * b.x; m3 += w2 * b.y;
                a = h2f(v3.x); b = h2f(v3.y);
                m0 += w3 * a.x; m1 += w3 * a.y; m2 += w3 * b.x; m3 += w3 * b.y;
                a = h2f(v4.x); b = h2f(v4.y);
                m0 += w4 * a.x; m1 += w4 * a.y; m2 += w4 * b.x; m3 += w4 * b.y;
                if (SKIP) {
                    float ws = h2f(q1.z).x;
                    a = h2f(vsk.x); b = h2f(vsk.y);
                    mS0 += ws * a.x; mS1 += ws * a.y; mS2 += ws * b.x; mS3 += ws * b.y;
                }
                q0 = nq0; q1 = nq1;
            }
        }

        // reduce across the 8 groups (lane bits 3,4,5)
        m0 += __shfl_xor(m0, 8, 64); m0 += __shfl_xor(m0, 16, 64); m0 += __shfl_xor(m0, 32, 64);
        m1 += __shfl_xor(m1, 8, 64); m1 += __shfl_xor(m1, 16, 64); m1 += __shfl_xor(m1, 32, 64);
        m2 += __shfl_xor(m2, 8, 64); m2 += __shfl_xor(m2, 16, 64); m2 += __shfl_xor(m2, 32, 64);
        m3 += __shfl_xor(m3, 8, 64); m3 += __shfl_xor(m3, 16, 64); m3 += __shfl_xor(m3, 32, 64);
        if (SKIP) {
            mS0 += __shfl_xor(mS0, 8, 64); mS0 += __shfl_xor(mS0, 16, 64); mS0 += __shfl_xor(mS0, 32, 64);
            mS1 += __shfl_xor(mS1, 8, 64); mS1 += __shfl_xor(mS1, 16, 64); mS1 += __shfl_xor(mS1, 32, 64);
            mS2 += __shfl_xor(mS2, 8, 64); mS2 += __shfl_xor(mS2, 16, 64); mS2 += __shfl_xor(mS2, 32, 64);
            mS3 += __shfl_xor(mS3, 8, 64); mS3 += __shfl_xor(mS3, 16, 64); mS3 += __shfl_xor(mS3, 32, 64);
        }

        const float invd = 1.0f / fmaxf((float)d, 1.0f);
        if (grp == 0) {
            float4 rv = ((const float4*)(R + (size_t)n * 32))[ch4];
            float v0 = m0 * invd + rv.x;
            float v1 = m1 * invd + rv.y;
            float v2 = m2 * invd + rv.z;
            float v3 = m3 * invd + rv.w;
            ((float4*)(c + (size_t)n * 32))[ch4] = make_float4(v0, v1, v2, v3);
            atomicAdd(&sh[4 * ch4 + 0], v0);
            atomicAdd(&sh[4 * ch4 + 1], v1);
            atomicAdd(&sh[4 * ch4 + 2], v2);
            atomicAdd(&sh[4 * ch4 + 3], v3);
            atomicAdd(&sh[32 + 4 * ch4 + 0], v0 * v0);
            atomicAdd(&sh[32 + 4 * ch4 + 1], v1 * v1);
            atomicAdd(&sh[32 + 4 * ch4 + 2], v2 * v2);
            atomicAdd(&sh[32 + 4 * ch4 + 3], v3 * v3);
            if (SKIP) {
                float4 rs = ((const float4*)(Rs + (size_t)n * 32))[ch4];
                float s0 = mS0 * invd + rs.x;
                float s1 = mS1 * invd + rs.y;
                float s2 = mS2 * invd + rs.z;
                float s3 = mS3 * invd + rs.w;
                ((float4*)(cs + (size_t)n * 32))[ch4] = make_float4(s0, s1, s2, s3);
                atomicAdd(&sh[64 + 4 * ch4 + 0], s0);
                atomicAdd(&sh[64 + 4 * ch4 + 1], s1);
                atomicAdd(&sh[64 + 4 * ch4 + 2], s2);
                atomicAdd(&sh[64 + 4 * ch4 + 3], s3);
                atomicAdd(&sh[96 + 4 * ch4 + 0], s0 * s0);
                atomicAdd(&sh[96 + 4 * ch4 + 1], s1 * s1);
                atomicAdd(&sh[96 + 4 * ch4 + 2], s2 * s2);
                atomicAdd(&sh[96 + 4 * ch4 + 3], s3 * s3);
            }
        }
    }
    __syncthreads();
    if (SKIP) { if (threadIdx.x < 128) atomicAdd(&stats[threadIdx.x], sh[threadIdx.x]); }
    else      { if (threadIdx.x < 64)  atomicAdd(&stats[threadIdx.x], sh[threadIdx.x]); }
}

// h = elu(bn(c1)); s = bn(cs). stats layout: [sum1|sq1|sumS|sqS]
__global__ void apply1_kernel(const float* __restrict__ c1, const float* __restrict__ cs,
                              const float* __restrict__ stats, const float* __restrict__ gam1,
                              const float* __restrict__ bet1, const float* __restrict__ gams,
                              const float* __restrict__ bets, float* __restrict__ h,
                              float* __restrict__ s_out) {
    int idx = blockIdx.x * blockDim.x + threadIdx.x;
    if (idx >= NN * 32) return;
    int ch = idx & 31;
    const float invN = 1.0f / (float)NN;
    float m1 = stats[ch] * invN;
    float v1 = stats[32 + ch] * invN - m1 * m1;
    float hv = gam1[ch] * (c1[idx] - m1) * rsqrtf(v1 + BN_EPS) + bet1[ch];
    h[idx] = hv > 0.f ? hv : (__expf(hv) - 1.f);
    float ms = stats[64 + ch] * invN;
    float vs = stats[96 + ch] * invN - ms * ms;
    s_out[idx] = gams[ch] * (cs[idx] - ms) * rsqrtf(vs + BN_EPS) + bets[ch];
}

// out = elu(bn(c2) + s)
__global__ void apply2_kernel(const float* __restrict__ c2, const float* __restrict__ s_in,
                              const float* __restrict__ stats, const float* __restrict__ gam2,
                              const float* __restrict__ bet2, float* __restrict__ out) {
    int idx = blockIdx.x * blockDim.x + threadIdx.x;
    if (idx >= NN * 32) return;
    int ch = idx & 31;
    const float invN = 1.0f / (float)NN;
    float m = stats[ch] * invN;
    float v = stats[32 + ch] * invN - m * m;
    float o = gam2[ch] * (c2[idx] - m) * rsqrtf(v + BN_EPS) + bet2[ch] + s_in[idx];
    out[idx] = o > 0.f ? o : (__expf(o) - 1.f);
}

extern "C" void kernel_launch(void* const* d_in, const int* in_sizes, int n_in,
                              void* d_out, int out_size, void* d_ws, size_t ws_size,
                              hipStream_t stream) {
    const float* x     = (const float*)d_in[0];
    const float* ea    = (const float*)d_in[1];
    const float* g1    = (const float*)d_in[2];
    const float* mu1   = (const float*)d_in[3];
    const float* sig1  = (const float*)d_in[4];
    const float* root1 = (const float*)d_in[5];
    const float* b1    = (const float*)d_in[6];
    const float* gam1  = (const float*)d_in[7];
    const float* bet1  = (const float*)d_in[8];
    const float* g2    = (const float*)d_in[9];
    const float* mu2   = (const float*)d_in[10];
    const float* sig2  = (const float*)d_in[11];
    const float* root2 = (const float*)d_in[12];
    const float* b2    = (const float*)d_in[13];
    const float* gam2  = (const float*)d_in[14];
    const float* bet2  = (const float*)d_in[15];
    const float* gs    = (const float*)d_in[16];
    const float* mus   = (const float*)d_in[17];
    const float* sigs  = (const float*)d_in[18];
    const float* roots = (const float*)d_in[19];
    const float* bs    = (const float*)d_in[20];
    const float* gams  = (const float*)d_in[21];
    const float* bets  = (const float*)d_in[22];
    const int*   ei    = (const int*)d_in[23];
    float* out = (float*)d_out;

    // ---- workspace layout ----
    char* w = (char*)d_ws;
    __half* PA   = (__half*)w;      w += (size_t)NN * 192 * 2;  // 19.2 MB (reused as PB)
    float*  R1   = (float*)w;       w += (size_t)NN * 32 * 4;   // (reused as R2)
    float*  Rs   = (float*)w;       w += (size_t)NN * 32 * 4;
    float*  c1   = (float*)w;       w += (size_t)NN * 32 * 4;   // (reused as c2)
    float*  cs   = (float*)w;       w += (size_t)NN * 32 * 4;
    float*  h    = (float*)w;       w += (size_t)NN * 32 * 4;
    float*  sbuf = (float*)w;       w += (size_t)NN * 32 * 4;
    EdgeRec* recs = (EdgeRec*)w;    w += (size_t)NE * 32;       // 25.6 MB
    int*    deg  = (int*)w;         w += (size_t)NN * 4;
    float*  stats = (float*)w;      w += 256 * 4;               // [0..127]=pass A, [128..191]=pass B
    int*    rowstart = (int*)w;     w += (size_t)(NN + 1) * 4;
    int*    cursor   = (int*)w;     w += (size_t)NN * 4;
    int*    bsum = (int*)w;         w += 256 * 4;
    float*  inv   = (float*)w;      w += 64 * 4;

    const int edgeBlocks  = (NE + 255) / 256;
    const int applyBlocks = (NN * 32 + 255) / 256;

    // deg and stats are contiguous -> one memset
    hipMemsetAsync(deg, 0, (size_t)NN * 4 + 256 * 4, stream);
    precompute_inv<<<1, 64, 0, stream>>>(sig1, sig2, sigs, inv);

    // ---- CSR build (once, shared by all 3 convs) ----
    hist_kernel<<<edgeBlocks, 256, 0, stream>>>(ei, deg);
    block_reduce_kernel<<<NB, 256, 0, stream>>>(deg, bsum);
    scan_partials_kernel<<<1, 256, 0, stream>>>(bsum);
    block_scan_kernel<<<NB, 256, 0, stream>>>(deg, bsum, rowstart, cursor);
    reorder_kernel<<<edgeBlocks, 256, 0, stream>>>(ei, ea, mu1, mu2, mus, inv, cursor,
                                                   (int4*)recs);

    // ---- pass A: conv1 + skip fused ----
    projA_kernel<<<512, 256, 0, stream>>>(x, g1, gs, root1, b1, roots, bs, PA, R1, Rs);
    agg_kernel<true, 0><<<2048, 256, 0, stream>>>((const int4*)recs, rowstart,
                                                  (const char*)PA, 384, R1, Rs, c1, cs, stats);
    apply1_kernel<<<applyBlocks, 256, 0, stream>>>(c1, cs, stats, gam1, bet1, gams, bets,
                                                   h, sbuf);

    // ---- pass B: conv2 on h, then out = elu(bn(c2) + s) ----
    projB_kernel<<<512, 192, 0, stream>>>(h, g2, root2, b2, PA, R1);  // PA/R1 reused
    agg_kernel<false, 5><<<2048, 256, 0, stream>>>((const int4*)recs, rowstart,
                                                   (const char*)PA, 320, R1, nullptr, c1,
                                                   nullptr, stats + 128);
    apply2_kernel<<<applyBlocks, 256, 0, stream>>>(c1, sbuf, stats + 128, gam2, bet2, out);
}